// Round 14
// baseline (1859.455 us; speedup 1.0000x reference)
//
#include <hip/hip_runtime.h>

// GRU decoder with Bahdanau attention, B=32, T=64, O=E=384, H=768.
// Persistent cooperative kernel, 3 grid barriers per step.
// r13 (best, 1854us) + ONE local change: attention context (wred) loop
// parallelized 4-way over t with o-pair u32 loads + 2x unroll
// (32 sequential loads -> ~8 overlapped windows). outp attn write moved
// to idle threads. No dependency/barrier/layout changes.

#define DEVI static __device__ __forceinline__
typedef float f32x4 __attribute__((ext_vector_type(4)));
typedef unsigned u32x4 __attribute__((ext_vector_type(4)));
typedef unsigned u32x2 __attribute__((ext_vector_type(2)));
typedef unsigned short ushort_t;

constexpr int ATTN_OFF = 786432;

// f32 ws offsets
constexpr int OFF_HALL  = 0;        // 65 x (768k,32b) h, rotated
constexpr int OFF_U     = 1597440;  // (b,k) 32*768 uncached
constexpr int OFF_WALL  = 1622016;  // 64 x (b,o) w_i, rotated
constexpr int OFF_HISTF = 2408448;  // 64 x (b,o) f32 outputs, rotated
constexpr int OFF_GH    = 3194880;  // (row,b) 2304*32 uncached
constexpr int OFF_GIE   = 3268608;  // (row,b) 2304*32 uncached
constexpr int OFF_FE    = 3342336;  // (row,b) 384*32 uncached
constexpr int OFF_GE    = 3354624;  // (row,b) 768*32 uncached
constexpr int OFF_FP    = 3379200;  // (row,b) 384*32 uncached
constexpr int OFF_CP    = 3391488;  // (row,b) 768*32 uncached
constexpr int OFF_GHM   = 3416064;  // Gh (768,768) f32
constexpr int OFF_GWM   = 4005888;  // Gw (768,384) f32
constexpr int OFF_GEM   = 4300800;  // Ge (768,384) f32
constexpr int OFF_GB    = 4595712;  // 768
constexpr int OFF_V1    = 4596480;  // M = sum|v|
constexpr int OFF_BAR   = 4596512;  // 1152 u32 (grp x32, super, gen)
constexpr int OFF_F32END= 4597664;
// ushort offsets into w16 = (ushort*)(ws + OFF_F32END)
constexpr int O16_CALL = 0;         // 64 x (b,k) bf16 c_t, rotated
constexpr int O16_HIST = 1572864;   // 64 x (b,o) bf16 hist_t, rotated

DEVI float fast_tanh(float x) {
  float a = __builtin_fabsf(x);
  float e = __expf(-2.0f * a);
  float r = __fdividef(1.0f - e, 1.0f + e);
  return __builtin_copysignf(r, x);
}
DEVI float sigmoidf_(float x) { return __fdividef(1.0f, 1.0f + __expf(-x)); }
DEVI float bflo(unsigned u) { return __uint_as_float(u << 16); }
DEVI float bfhi(unsigned u) { return __uint_as_float(u & 0xffff0000u); }
DEVI unsigned f2bf(float f) {
  unsigned u = __float_as_uint(f);
  return (u + 0x7fffu + ((u >> 16) & 1u)) >> 16;
}

DEVI float nc_ld_f1(const float* p) {
  float r;
  asm volatile("global_load_dword %0, %1, off sc0 sc1\n\ts_waitcnt vmcnt(0)"
               : "=&v"(r) : "v"(p) : "memory");
  return r;
}
DEVI f32x4 nc_ld4(const float* p) {
  f32x4 r;
  asm volatile("global_load_dwordx4 %0, %1, off sc0 sc1\n\ts_waitcnt vmcnt(0)"
               : "=&v"(r) : "v"(p) : "memory");
  return r;
}
DEVI void nc_ld4x2(const float* p0, const float* p1, f32x4& r0, f32x4& r1) {
  asm volatile(
      "global_load_dwordx4 %0, %2, off sc0 sc1\n\t"
      "global_load_dwordx4 %1, %3, off sc0 sc1\n\t"
      "s_waitcnt vmcnt(0)"
      : "=&v"(r0), "=&v"(r1) : "v"(p0), "v"(p1) : "memory");
}
DEVI void nc_st4(float* p, f32x4 v) {
  asm volatile("global_store_dwordx4 %0, %1, off sc0 sc1" :: "v"(p), "v"(v) : "memory");
}
DEVI void nc_st2u(ushort_t* p, u32x2 v) {
  asm volatile("global_store_dwordx2 %0, %1, off sc0 sc1" :: "v"(p), "v"(v) : "memory");
}
DEVI void nc_st_f1(float* p, float v_) {
  asm volatile("global_store_dword %0, %1, off sc0 sc1" :: "v"(p), "v"(v_) : "memory");
}

// round-5 3-hop barrier: grp (reset) -> super (reset) -> gen (monotonic).
// Pollers poll gen: a line no one increments during arrival -> uncontended.
DEVI void gridbar(unsigned* bar) {
  asm volatile("s_waitcnt vmcnt(0)" ::: "memory");
  __syncthreads();
  if (threadIdx.x == 0) {
    unsigned* super = bar + 1024;
    unsigned* gen   = bar + 1056;
    unsigned g = __hip_atomic_load(gen, __ATOMIC_RELAXED, __HIP_MEMORY_SCOPE_AGENT);
    int grp = (int)(blockIdx.x >> 3);
    unsigned a = __hip_atomic_fetch_add(bar + grp * 32, 1u, __ATOMIC_RELAXED, __HIP_MEMORY_SCOPE_AGENT);
    bool released = false;
    if (a == 7u) {
      __hip_atomic_store(bar + grp * 32, 0u, __ATOMIC_RELAXED, __HIP_MEMORY_SCOPE_AGENT);
      unsigned s = __hip_atomic_fetch_add(super, 1u, __ATOMIC_RELAXED, __HIP_MEMORY_SCOPE_AGENT);
      if (s == 31u) {
        __hip_atomic_store(super, 0u, __ATOMIC_RELAXED, __HIP_MEMORY_SCOPE_AGENT);
        __hip_atomic_fetch_add(gen, 1u, __ATOMIC_RELAXED, __HIP_MEMORY_SCOPE_AGENT);
        released = true;
      }
    }
    if (!released) {
      while (__hip_atomic_load(gen, __ATOMIC_RELAXED, __HIP_MEMORY_SCOPE_AGENT) == g) {
        __builtin_amdgcn_s_sleep(1);
      }
    }
  }
  __syncthreads();
}

// ---------- precompute Gh/Gw/Ge (f32) + gb ----------
__global__ __launch_bounds__(256) void kprepG(const float* __restrict__ attn_W,
                                              const float* __restrict__ fcW,
                                              const float* __restrict__ fcb,
                                              float* __restrict__ ws) {
  int bid = blockIdx.x, tid = threadIdx.x;
  if (bid < 288) {
    int rt = bid / 6, kt = bid % 6;
    int r0 = rt * 16;
    int kg = kt * 256 + tid;
    float acc[16];
#pragma unroll
    for (int q = 0; q < 16; ++q) acc[q] = 0.f;
    for (int o = 0; o < 384; ++o) {
      float f = fcW[o * 1536 + kg];
#pragma unroll
      for (int q = 0; q < 16; ++q)
        acc[q] = fmaf(attn_W[(r0 + q) * 1152 + 768 + o], f, acc[q]);
    }
#pragma unroll
    for (int q = 0; q < 16; ++q) {
      int r = r0 + q;
      if (kg < 768)       ws[OFF_GHM + r * 768 + kg] = acc[q];
      else if (kg < 1152) ws[OFF_GWM + r * 384 + (kg - 768)] = acc[q];
      else                ws[OFF_GEM + r * 384 + (kg - 1152)] = acc[q];
    }
  } else {
    for (int r = tid; r < 768; r += 256) {
      float a = 0.f;
      for (int o = 0; o < 384; ++o) a = fmaf(attn_W[r * 1152 + 768 + o], fcb[o], a);
      ws[OFF_GB + r] = a;
    }
  }
}

// ---------- prep: h transpose, zeros, M, barrier ----------
__global__ __launch_bounds__(256) void kprep0(const float* __restrict__ hidden,
                                              const float* __restrict__ vW,
                                              float* __restrict__ ws) {
  ushort_t* w16 = (ushort_t*)(ws + OFF_F32END);
  int bid = blockIdx.x, tid = threadIdx.x;
  int gtid = bid * 256 + tid;
  if (gtid < 24576) {
    int k = gtid >> 5, b = gtid & 31;
    ws[OFF_HALL + gtid] = hidden[b * 768 + k];
  } else if (gtid < 36864) {
    ((unsigned*)(w16 + O16_CALL))[gtid - 24576] = 0u;
  } else if (gtid < 43008) {
    ((unsigned*)(w16 + O16_HIST))[gtid - 36864] = 0u;
  }
  if (gtid < 1152) ((unsigned*)(ws + OFF_BAR))[gtid] = 0u;
  if (bid == 0) {
    __shared__ float vred[256];
    float a = 0.f;
    for (int k = tid; k < 768; k += 256) a += __builtin_fabsf(vW[k]);
    vred[tid] = a;
    __syncthreads();
    for (int s2 = 128; s2 > 0; s2 >>= 1) {
      if (tid < s2) vred[tid] += vred[tid + s2];
      __syncthreads();
    }
    if (tid == 0) ws[OFF_V1] = vred[0];
  }
}

// ---------- main persistent cooperative kernel ----------
__global__ void __launch_bounds__(1024)
kmain(const int* __restrict__ target, const float* __restrict__ emb,
      const float* __restrict__ attn_W, const float* __restrict__ attn_b,
      const float* __restrict__ vW,
      const float* __restrict__ Wih, const float* __restrict__ Whh,
      const float* __restrict__ bih, const float* __restrict__ bhh,
      const float* __restrict__ fcW, const float* __restrict__ fcb,
      float* __restrict__ outp, float* __restrict__ ws) {
  const int bid = blockIdx.x, tid = threadIdx.x;
  const int wv = tid >> 6, lane = tid & 63;
  const int b32 = lane & 31, kh = lane >> 5;
  const int vb = ((bid & 7) << 5) | (bid >> 3);  // XCD-major
  const int xcd = vb >> 5, slot = vb & 31;
  unsigned* bar = (unsigned*)(ws + OFF_BAR);
  ushort_t* w16 = (ushort_t*)(ws + OFF_F32END);

  // ---- LDS: persistent weights + phase-workspace union ----
  __shared__ __align__(16) float sW_A[8 * 768];    // 24.6 KB (phase A rows)
  __shared__ __align__(16) float sW_B[16 * 384];   // 24.6 KB (gie rows)
  __shared__ __align__(16) float sW_GH[12 * 768];  // 36.9 KB (Whh rows, B-right)
  __shared__ __align__(16) float sW_C[14 * 384];   // 21.5 KB
  __shared__ __align__(16) float sUn[13536];       // 54.1 KB

  // ---- row partitions ----
  // Phase A: 1920 rows = 480 groups of 4 (u:0-767, c:768-1535, out:1536-1919)
  const int gbA = (vb * 480) >> 8, geA = ((vb + 1) * 480) >> 8;
  const int rbA = gbA * 4;
  const int nswA = geA - gbA;            // 1 or 2
  const int nRA = nswA * 4;              // 4 or 8
  const int lb  = xcd * 28 + (slot - 4); // valid when slot>=4
  const int rbB = (slot >= 4) ? (lb * 3456) / 224 : 0;
  const int reB = (slot >= 4) ? ((lb + 1) * 3456) / 224 : 0;
  const int nB  = reB - rbB;
  // gh: 2304 rows = 576 groups of 4 over 224 B-right blocks
  const int gbG = (slot >= 4) ? (lb * 576) / 224 : 0;
  const int geG = (slot >= 4) ? ((lb + 1) * 576) / 224 : 0;
  const int nswG = geG - gbG;            // 2 or 3
  const int nRG = nswG * 4;              // 8 or 12
  const int rbC = xcd * 144 + ((slot * 144) >> 5);
  const int reC = xcd * 144 + (((slot + 1) * 144) >> 5);

  // ---- one-time LDS weight load ----
  for (int lr = 0; lr < nRA; ++lr) {
    int row = rbA + lr;
    const float* src;
    if (row < 768)       src = attn_W + row * 1152;
    else if (row < 1536) src = ws + OFF_GHM + (row - 768) * 768;
    else                 src = fcW + (row - 1536) * 1536;
    if (tid < 768) sW_A[lr * 768 + tid] = src[tid];
  }
  if (slot >= 4) {
    for (int lr = 0; lr < nB; ++lr) {
      int row = rbB + lr;
      const float* src;
      if (row < 2304)      src = Wih + row * 768;
      else if (row < 2688) src = fcW + (row - 2304) * 1536 + 1152;
      else                 src = ws + OFF_GEM + (row - 2688) * 384;
      if (tid < 384) sW_B[lr * 384 + tid] = src[tid];
    }
    for (int lr = 0; lr < nRG; ++lr) {
      int row = gbG * 4 + lr;
      if (tid < 768) sW_GH[lr * 768 + tid] = Whh[row * 768 + tid];
    }
  }
  for (int lr = 0; lr < 14; ++lr) {
    const float* src = nullptr;
    if (lr < 9) {
      int grow = vb * 3 + (lr / 3) + (lr % 3) * 768;  // lr = jl*3+gg
      src = Wih + grow * 768 + 384;
    } else {
      int r = rbC + (lr - 9);
      if (r < reC) src = (r < 384) ? fcW + r * 1536 + 768
                                   : ws + OFF_GWM + (r - 384) * 384;
    }
    if (src && tid < 384) sW_C[lr * 384 + tid] = src[tid];
  }
  __syncthreads();

  const float Mv = ws[OFF_V1];
  const int k0 = wv * 48 + kh * 24;

  for (int i = 0; i < 64; ++i) {
    // ======== Phase A (FUSED single pass): u, c_i, out_{i-1} ====
    {
      float* part_  = sUn;          // 4096 (16 waves x 8 rows x 32)
      float* stage  = sUn + 4096;   // 256
      float* stage2 = sUn + 4352;   // 256
      float xr[24];
      const float* hb = ws + OFF_HALL + i * 24576 + b32;  // (k,b) cached
#pragma unroll
      for (int q = 0; q < 24; ++q) xr[q] = hb[(k0 + q) * 32];

      float a[8];
#pragma unroll
      for (int r = 0; r < 8; ++r) a[r] = 0.f;
#pragma unroll
      for (int r = 0; r < 8; ++r) {
        if (r < nRA) {
          int row = rbA + r;
          if (!(i == 0 && row >= 768)) {
            const float* wp = &sW_A[r * 768 + k0];
            float acc = 0.f;
#pragma unroll
            for (int q = 0; q < 6; ++q) {
              f32x4 w = *(const f32x4*)(wp + q * 4);
              acc = fmaf(w[0], xr[q * 4 + 0], acc);
              acc = fmaf(w[1], xr[q * 4 + 1], acc);
              acc = fmaf(w[2], xr[q * 4 + 2], acc);
              acc = fmaf(w[3], xr[q * 4 + 3], acc);
            }
            a[r] = acc;
          }
        }
      }
#pragma unroll
      for (int r = 0; r < 8; ++r) a[r] += __shfl_xor(a[r], 32);
      if (kh == 0) {
#pragma unroll
        for (int r = 0; r < 8; ++r) part_[wv * 256 + r * 32 + b32] = a[r];
      }
      __syncthreads();
      if (tid < 256) {
        int rr = tid >> 5, bb = tid & 31;
        float sum = 0.f;
#pragma unroll
        for (int w2 = 0; w2 < 16; ++w2) sum += part_[w2 * 256 + tid];
        if (rr < nRA) {
          int row = rbA + rr;
          if (row < 768) sum += attn_b[row];
          stage[rr * 32 + bb] = sum;
        }
      } else if (tid < 320) {
        int t2 = tid - 256, rr = t2 >> 3, bq = t2 & 7;
        if (rr < nRA && i > 0) {
          int row = rbA + rr;
          if (row >= 768) {
            const float* src = row < 1536
                ? ws + OFF_CP + (row - 768) * 32 + bq * 4
                : ws + OFF_FP + (row - 1536) * 32 + bq * 4;
            *(f32x4*)&stage2[rr * 32 + bq * 4] = nc_ld4(src);
          }
        }
      }
      __syncthreads();
      // stores: tid<64, one 4-row group per 32 threads (groups are type-pure)
      if (tid < 64) {
        int gsel = tid >> 5, sub = tid & 31;
        if (gsel < nswA) {
          int row0 = rbA + gsel * 4;
          int e0 = gsel * 4;
          if (row0 < 768) {
            f32x4 v = {stage[e0 * 32 + sub], stage[(e0 + 1) * 32 + sub],
                       stage[(e0 + 2) * 32 + sub], stage[(e0 + 3) * 32 + sub]};
            nc_st4(ws + OFF_U + sub * 768 + row0, v);
          } else if (i > 0) {
            float v0 = stage[e0 * 32 + sub] + stage2[e0 * 32 + sub];
            float v1 = stage[(e0 + 1) * 32 + sub] + stage2[(e0 + 1) * 32 + sub];
            float v2 = stage[(e0 + 2) * 32 + sub] + stage2[(e0 + 2) * 32 + sub];
            float v3 = stage[(e0 + 3) * 32 + sub] + stage2[(e0 + 3) * 32 + sub];
            u32x2 pk;
            pk[0] = f2bf(v0) | (f2bf(v1) << 16);
            pk[1] = f2bf(v2) | (f2bf(v3) << 16);
            if (row0 < 1536) {
              nc_st2u(w16 + O16_CALL + i * 24576 + sub * 768 + (row0 - 768), pk);
            } else {
              nc_st2u(w16 + O16_HIST + i * 12288 + sub * 384 + (row0 - 1536), pk);
              f32x4 vf = {v0, v1, v2, v3};
              nc_st4(ws + OFF_HISTF + i * 12288 + sub * 384 + (row0 - 1536), vf);
            }
          }
        }
      }
    }
    gridbar(bar);

    // ======== Phase B: attention (32 blocks) | gie + gh GEMM (224 blocks) ====
    if (slot < 4) {
      const int bb = xcd * 4 + (vb & 3);
      float* u_s   = sUn;           // 768
      float* p_l   = sUn + 768;     // 64
      float* d_l   = sUn + 832;     // 16 (pad)
      float* wred2 = sUn + 848;     // 1536 (4 t-parities x 384)
      if (tid < 192) *(f32x4*)&u_s[tid * 4] = nc_ld4(ws + OFF_U + bb * 768 + tid * 4);
      if (tid < 64) p_l[tid] = 0.f;
      __syncthreads();
      const int tl = tid >> 5, kc = tid & 31;
      float u_r[24], v_r[24];
#pragma unroll
      for (int q = 0; q < 24; ++q) {
        u_r[q] = u_s[kc * 24 + q];
        v_r[q] = vW[kc * 24 + q];
      }
#pragma unroll
      for (int rr2 = 0; rr2 < 2; ++rr2) {
        int t = rr2 * 32 + tl;
        float s = 0.f;
        if (t <= i) {
          const ushort_t* cb = w16 + O16_CALL + t * 24576 + bb * 768 + kc * 24;  // cached
          u32x4 c0 = ((const u32x4*)cb)[0];
          u32x4 c1 = ((const u32x4*)cb)[1];
          u32x4 c2 = ((const u32x4*)cb)[2];
#pragma unroll
          for (int j = 0; j < 4; ++j) {
            s = fmaf(fast_tanh(u_r[2 * j] + bflo(c0[j])), v_r[2 * j], s);
            s = fmaf(fast_tanh(u_r[2 * j + 1] + bfhi(c0[j])), v_r[2 * j + 1], s);
            s = fmaf(fast_tanh(u_r[8 + 2 * j] + bflo(c1[j])), v_r[8 + 2 * j], s);
            s = fmaf(fast_tanh(u_r[8 + 2 * j + 1] + bfhi(c1[j])), v_r[8 + 2 * j + 1], s);
            s = fmaf(fast_tanh(u_r[16 + 2 * j] + bflo(c2[j])), v_r[16 + 2 * j], s);
            s = fmaf(fast_tanh(u_r[16 + 2 * j + 1] + bfhi(c2[j])), v_r[16 + 2 * j + 1], s);
          }
        }
#pragma unroll
        for (int d2 = 16; d2 >= 1; d2 >>= 1) s += __shfl_xor(s, d2);
        if (kc == 0 && t <= i) p_l[t] = __expf(s - Mv);
      }
      __syncthreads();
      // wave-parallel denominator
      if (tid < 64) {
        float pv = p_l[tid];
#pragma unroll
        for (int d = 1; d < 64; d <<= 1) pv += __shfl_xor(pv, d);
        if (tid == 0) d_l[0] = __fdividef(1.0f, pv);
      }
      __syncthreads();
      float dinv = d_l[0];
      // attn-weight outputs on otherwise-idle threads
      if (tid >= 768 && tid < 832) {
        int t = tid - 768;
        if (t <= i)
          outp[ATTN_OFF + bb * 2080 + (i * (i + 1)) / 2 + t] = p_l[t] * dinv;
      }
      // context: 4-way t-parallel, o-pair loads, 2x unrolled
      if (tid < 768) {
        int opair = tid % 192, tpar = tid / 192;  // tpar 0..3
        int o0 = opair * 2;
        const ushort_t* hbase = w16 + O16_HIST + bb * 384 + o0;
        float a0 = 0.f, a1 = 0.f;
        int t = tpar;
        for (; t + 4 <= i; t += 8) {
          unsigned hv0 = *(const unsigned*)(hbase + t * 12288);
          unsigned hv1 = *(const unsigned*)(hbase + (t + 4) * 12288);
          float p0 = p_l[t], p1 = p_l[t + 4];
          a0 = fmaf(p0, bflo(hv0), a0);
          a1 = fmaf(p0, bfhi(hv0), a1);
          a0 = fmaf(p1, bflo(hv1), a0);
          a1 = fmaf(p1, bfhi(hv1), a1);
        }
        if (t <= i) {
          unsigned hv = *(const unsigned*)(hbase + t * 12288);
          float p = p_l[t];
          a0 = fmaf(p, bflo(hv), a0);
          a1 = fmaf(p, bfhi(hv), a1);
        }
        wred2[tpar * 384 + o0]     = a0;
        wred2[tpar * 384 + o0 + 1] = a1;
      }
      __syncthreads();
      if (tid < 96) {
        f32x4 v;
#pragma unroll
        for (int e = 0; e < 4; ++e) {
          int o = tid * 4 + e;
          v[e] = (wred2[o] + wred2[384 + o] + wred2[768 + o] + wred2[1152 + o]) * dinv;
        }
        nc_st4(ws + OFF_WALL + i * 12288 + bb * 384 + tid * 4, v);
      }
    } else {
      float* part_  = sUn;          // gie: 2048 / gh: 6144
      float* stageB = sUn + 2048;   // 512
      float* ghst   = sUn + 8192;   // 384
      const int gl = wv >> 2, kq = wv & 3;
      const int tok = target[b32 * 65 + i];
      const int koff = kq * 96 + kh * 48;
      const float* xe = emb + tok * 384 + koff;
      f32x4 x_[12];
#pragma unroll
      for (int q = 0; q < 12; ++q) x_[q] = *(const f32x4*)(xe + q * 4);
      float a[4];
#pragma unroll
      for (int r = 0; r < 4; ++r) {
        int lr = gl * 4 + r;
        float acc = 0.f;
        if (lr < nB) {
          const float* wp = &sW_B[lr * 384 + koff];
#pragma unroll
          for (int q = 0; q < 12; ++q) {
            f32x4 w = *(const f32x4*)(wp + q * 4);
            acc = fmaf(w[0], x_[q][0], acc);
            acc = fmaf(w[1], x_[q][1], acc);
            acc = fmaf(w[2], x_[q][2], acc);
            acc = fmaf(w[3], x_[q][3], acc);
          }
        }
        a[r] = acc;
      }
#pragma unroll
      for (int r = 0; r < 4; ++r) a[r] += __shfl_xor(a[r], 32);
      if (kh == 0) {
#pragma unroll
        for (int r = 0; r < 4; ++r)
          part_[((gl * 4 + r) * 4 + kq) * 32 + b32] = a[r];
      }
      __syncthreads();
      if (tid < 512) {
        int glr = tid >> 5, bb = tid & 31;
        if (glr < nB) {
          float sum = part_[(glr * 4 + 0) * 32 + bb] + part_[(glr * 4 + 1) * 32 + bb]
                    + part_[(glr * 4 + 2) * 32 + bb] + part_[(glr * 4 + 3) * 32 + bb];
          int row = rbB + glr;
          if (row < 2304) sum += bih[row];
          else if (row < 2688) sum += fcb[row - 2304];
          else sum += ws[OFF_GB + (row - 2688)];
          stageB[glr * 32 + bb] = sum;
        }
      }
      __syncthreads();
      if (tid < 128) {
        int r16 = tid >> 3, bq = tid & 7;
        if (r16 < nB) {
          int row = rbB + r16;
          f32x4 v = *(f32x4*)&stageB[r16 * 32 + bq * 4];
          float* dst;
          if (row < 2304) dst = ws + OFF_GIE + row * 32 + bq * 4;
          else if (row < 2688) dst = ws + OFF_FE + (row - 2304) * 32 + bq * 4;
          else dst = ws + OFF_GE + (row - 2688) * 32 + bq * 4;
          nc_st4(dst, v);
        }
      }
      __syncthreads();
      // ---- gh pass (FUSED): Whh·h_i + bhh, up to 12 rows in one pass ----
      {
        float xr2[24];
        const float* hb2 = ws + OFF_HALL + i * 24576 + b32;  // cached
#pragma unroll
        for (int q = 0; q < 24; ++q) xr2[q] = hb2[(k0 + q) * 32];
        float a2[12];
#pragma unroll
        for (int r = 0; r < 12; ++r) a2[r] = 0.f;
#pragma unroll
        for (int r = 0; r < 12; ++r) {
          if (r < nRG) {
            const float* wp = &sW_GH[r * 768 + k0];
            float acc = 0.f;
#pragma unroll
            for (int q = 0; q < 6; ++q) {
              f32x4 w = *(const f32x4*)(wp + q * 4);
              acc = fmaf(w[0], xr2[q * 4 + 0], acc);
              acc = fmaf(w[1], xr2[q * 4 + 1], acc);
              acc = fmaf(w[2], xr2[q * 4 + 2], acc);
              acc = fmaf(w[3], xr2[q * 4 + 3], acc);
            }
            a2[r] = acc;
          }
        }
#pragma unroll
        for (int r = 0; r < 12; ++r) a2[r] += __shfl_xor(a2[r], 32);
        if (kh == 0) {
#pragma unroll
          for (int r = 0; r < 12; ++r) part_[wv * 384 + r * 32 + b32] = a2[r];
        }
        __syncthreads();
        if (tid < 384) {
          int rr = tid >> 5, bb = tid & 31;
          if (rr < nRG) {
            float sum = 0.f;
#pragma unroll
            for (int w2 = 0; w2 < 16; ++w2) sum += part_[w2 * 384 + tid];
            ghst[rr * 32 + bb] = sum + bhh[gbG * 4 + rr];
          }
        }
        __syncthreads();
        if (tid < 96) {
          int rr = tid >> 3, bq = tid & 7;
          if (rr < nRG)
            nc_st4(ws + OFF_GH + (gbG * 4 + rr) * 32 + bq * 4,
                   *(f32x4*)&ghst[rr * 32 + bq * 4]);
        }
      }
    }
    gridbar(bar);

    // ======== Phase C: w staging, giw, fpart/cpart, gates ====
    {
      float* w_lds   = sUn;           // 12416 (stride 388)
      float* g_lds   = sUn + 12416;   // 576
      float* giw_lds = sUn + 12992;   // 288
      float* fpst    = sUn + 13280;   // 160
      float* gat     = sUn + 13440;   // 96
      {
        int b = tid >> 5, c = tid & 31;
        const float* src = ws + OFF_WALL + i * 12288 + tid * 12;  // cached coalesced
        float* dst = w_lds + b * 388 + c * 12;
        *(f32x4*)&dst[0] = *(const f32x4*)(src);
        *(f32x4*)&dst[4] = *(const f32x4*)(src + 4);
        *(f32x4*)&dst[8] = *(const f32x4*)(src + 8);
      }
      __syncthreads();
      if (wv < 9) {
        int jl = wv / 3, gg = wv % 3;
        const float* wp = &sW_C[(jl * 3 + gg) * 384 + kh * 192];
        const float* xp = w_lds + b32 * 388 + kh * 192;
        float acc = 0.f;
#pragma unroll 8
        for (int q = 0; q < 48; ++q) {
          f32x4 wq4 = *(const f32x4*)(wp + q * 4);
          f32x4 xq4 = *(const f32x4*)(xp + q * 4);
          acc = fmaf(wq4[0], xq4[0], acc); acc = fmaf(wq4[1], xq4[1], acc);
          acc = fmaf(wq4[2], xq4[2], acc); acc = fmaf(wq4[3], xq4[3], acc);
        }
        acc += __shfl_xor(acc, 32);
        if (kh == 0) giw_lds[(jl * 3 + gg) * 32 + b32] = acc;
      } else if (wv < 14) {
        int r = rbC + (wv - 9);
        if (r < reC) {
          const float* wp = &sW_C[(9 + (wv - 9)) * 384 + kh * 192];
          const float* xp = w_lds + b32 * 388 + kh * 192;
          float acc = 0.f;
#pragma unroll 8
          for (int q = 0; q < 48; ++q) {
            f32x4 wq4 = *(const f32x4*)(wp + q * 4);
            f32x4 xq4 = *(const f32x4*)(xp + q * 4);
            acc = fmaf(wq4[0], xq4[0], acc); acc = fmaf(wq4[1], xq4[1], acc);
            acc = fmaf(wq4[2], xq4[2], acc); acc = fmaf(wq4[3], xq4[3], acc);
          }
          acc += __shfl_xor(acc, 32);
          if (kh == 0) fpst[(wv - 9) * 32 + b32] = acc;
        }
      } else {
        int t2 = tid - 896;
        if (t2 < 72) {
          int q0 = 2 * t2, q1 = 2 * t2 + 1;
          const float* pa;
          const float* pb;
          {
            int row = q0 >> 3, bq = q0 & 7;
            int rr2 = row < 9 ? row : row - 9;
            int r = vb * 3 + (rr2 % 3) + (rr2 / 3) * 768;
            pa = ws + (row < 9 ? OFF_GIE : OFF_GH) + r * 32 + bq * 4;
          }
          {
            int row = q1 >> 3, bq = q1 & 7;
            int rr2 = row < 9 ? row : row - 9;
            int r = vb * 3 + (rr2 % 3) + (rr2 / 3) * 768;
            pb = ws + (row < 9 ? OFF_GIE : OFF_GH) + r * 32 + bq * 4;
          }
          f32x4 v0, v1;
          nc_ld4x2(pa, pb, v0, v1);
          *(f32x4*)&g_lds[q0 * 4] = v0;
          *(f32x4*)&g_lds[q1 * 4] = v1;
        }
      }
      __syncthreads();
      if (tid < 96) {
        int jl = tid >> 5, bb = tid & 31;
        int j = vb * 3 + jl;
        float gi_r = g_lds[jl * 32 + bb];
        float gi_z = g_lds[(3 + jl) * 32 + bb];
        float gi_n = g_lds[(6 + jl) * 32 + bb];
        float gh_r = g_lds[(9 + jl) * 32 + bb];
        float gh_z = g_lds[(12 + jl) * 32 + bb];
        float gh_n = g_lds[(15 + jl) * 32 + bb];
        float giw_r = giw_lds[(jl * 3 + 0) * 32 + bb];
        float giw_z = giw_lds[(jl * 3 + 1) * 32 + bb];
        float giw_n = giw_lds[(jl * 3 + 2) * 32 + bb];
        float hold = ws[OFF_HALL + i * 24576 + j * 32 + bb];
        float r_ = sigmoidf_(gi_r + giw_r + gh_r);
        float z_ = sigmoidf_(gi_z + giw_z + gh_z);
        float n_ = fast_tanh(fmaf(r_, gh_n, gi_n + giw_n));
        gat[jl * 32 + bb] = (1.0f - z_) * n_ + z_ * hold;
      } else if (tid >= 96 && tid < 136) {
        int t2 = tid - 96, rl = t2 >> 3, bq = t2 & 7;
        int r = rbC + rl;
        if (r < reC) {
          const float* addp = r < 384 ? ws + OFF_FE + r * 32 + bq * 4
                                      : ws + OFF_GE + (r - 384) * 32 + bq * 4;
          f32x4 ad = nc_ld4(addp);
          f32x4 v;
#pragma unroll
          for (int e = 0; e < 4; ++e) v[e] = fpst[rl * 32 + bq * 4 + e] + ad[e];
          float* dst = r < 384 ? ws + OFF_FP + r * 32 + bq * 4
                               : ws + OFF_CP + (r - 384) * 32 + bq * 4;
          nc_st4(dst, v);
        }
      }
      __syncthreads();
      if (tid < 24) {
        int jl3 = tid >> 3, bq = tid & 7;
        f32x4 v = *(f32x4*)&gat[jl3 * 32 + bq * 4];
        nc_st4(ws + OFF_HALL + (i + 1) * 24576 + (vb * 3 + jl3) * 32 + bq * 4, v);
      }
    }
    gridbar(bar);
  }

  // ======== epilogue: out_63 = F_h h_64 + fp_63 ====
  if (slot < 3) {
    int o = xcd * 48 + slot * 16 + wv;
    const float* hcol = ws + OFF_HALL + 64 * 24576 + b32;
    const float* wrow = fcW + o * 1536 + kh * 384;
    float acc = 0.f;
#pragma unroll 4
    for (int q = 0; q < 96; ++q) {
      f32x4 wq = *(const f32x4*)(wrow + q * 4);
      int k = kh * 384 + q * 4;
      acc = fmaf(wq[0], hcol[k * 32], acc);
      acc = fmaf(wq[1], hcol[(k + 1) * 32], acc);
      acc = fmaf(wq[2], hcol[(k + 2) * 32], acc);
      acc = fmaf(wq[3], hcol[(k + 3) * 32], acc);
    }
    acc += __shfl_xor(acc, 32);
    if (kh == 0) {
      float fp = nc_ld_f1(ws + OFF_FP + o * 32 + b32);
      outp[b32 * 24576 + o * 64 + 63] = acc + fp;
    }
  }
  // ======== final transpose: outputs[b][o][t], t=0..62 from HISTF ====
  if (tid < 48) {
    int pair = vb * 48 + tid;
    int b = pair / 384, o = pair - b * 384;
    const float* src = ws + OFF_HISTF + b * 384 + o;
    float* dst = outp + b * 24576 + o * 64;
#pragma unroll 7
    for (int t = 0; t < 63; ++t) dst[t] = src[(t + 1) * 12288];
  }
}

extern "C" void kernel_launch(void* const* d_in, const int* in_sizes, int n_in,
                              void* d_out, int out_size, void* d_ws, size_t ws_size,
                              hipStream_t stream) {
  const int*   target = (const int*)d_in[0];
  const float* hidden = (const float*)d_in[1];
  // d_in[2] = teacher_forcing_ratio (== 1, deterministic path)
  const float* emb    = (const float*)d_in[3];
  const float* attn_W = (const float*)d_in[4];
  const float* attn_b = (const float*)d_in[5];
  const float* vW     = (const float*)d_in[6];
  const float* Wih    = (const float*)d_in[7];
  const float* Whh    = (const float*)d_in[8];
  const float* bih    = (const float*)d_in[9];
  const float* bhh    = (const float*)d_in[10];
  const float* fcW    = (const float*)d_in[11];
  const float* fcb    = (const float*)d_in[12];
  float* outp = (float*)d_out;
  float* ws   = (float*)d_ws;

  kprepG<<<289, 256, 0, stream>>>(attn_W, fcW, fcb, ws);
  kprep0<<<256, 256, 0, stream>>>(hidden, vW, ws);

  void* args[] = {(void*)&target, (void*)&emb, (void*)&attn_W, (void*)&attn_b,
                  (void*)&vW, (void*)&Wih, (void*)&Whh, (void*)&bih, (void*)&bhh,
                  (void*)&fcW, (void*)&fcb, (void*)&outp, (void*)&ws};
  hipLaunchCooperativeKernel((const void*)kmain, dim3(256), dim3(1024), args, 0, stream);
}

// Round 15
// 1756.702 us; speedup vs baseline: 1.0585x; 1.0585x over previous
//
#include <hip/hip_runtime.h>

// GRU decoder with Bahdanau attention, B=32, T=64, O=E=384, H=768.
// Persistent cooperative kernel, 3 grid barriers per step.
// r14 (1859us) + barrier = 3-hop EPOCH-RING (split-safe, poll-on-gen,
// one increment per use on the poll line) + SPLIT at barrier 1:
// gie+gh blocks arrive but don't wait (their inputs are step-i-ready).

#define DEVI static __device__ __forceinline__
typedef float f32x4 __attribute__((ext_vector_type(4)));
typedef unsigned u32x4 __attribute__((ext_vector_type(4)));
typedef unsigned u32x2 __attribute__((ext_vector_type(2)));
typedef unsigned short ushort_t;

constexpr int ATTN_OFF = 786432;

// f32 ws offsets
constexpr int OFF_HALL  = 0;        // 65 x (768k,32b) h, rotated
constexpr int OFF_U     = 1597440;  // (b,k) 32*768 uncached
constexpr int OFF_WALL  = 1622016;  // 64 x (b,o) w_i, rotated
constexpr int OFF_HISTF = 2408448;  // 64 x (b,o) f32 outputs, rotated
constexpr int OFF_GH    = 3194880;  // (row,b) 2304*32 uncached
constexpr int OFF_GIE   = 3268608;  // (row,b) 2304*32 uncached
constexpr int OFF_FE    = 3342336;  // (row,b) 384*32 uncached
constexpr int OFF_GE    = 3354624;  // (row,b) 768*32 uncached
constexpr int OFF_FP    = 3379200;  // (row,b) 384*32 uncached
constexpr int OFF_CP    = 3391488;  // (row,b) 768*32 uncached
constexpr int OFF_GHM   = 3416064;  // Gh (768,768) f32
constexpr int OFF_GWM   = 4005888;  // Gw (768,384) f32
constexpr int OFF_GEM   = 4300800;  // Ge (768,384) f32
constexpr int OFF_GB    = 4595712;  // 768
constexpr int OFF_V1    = 4596480;  // M = sum|v|
constexpr int OFF_BAR   = 4596512;  // 2176 u32 epoch-ring (4 slots)
constexpr int OFF_F32END= 4598688;
// ushort offsets into w16 = (ushort*)(ws + OFF_F32END)
constexpr int O16_CALL = 0;         // 64 x (b,k) bf16 c_t, rotated
constexpr int O16_HIST = 1572864;   // 64 x (b,o) bf16 hist_t, rotated

DEVI float fast_tanh(float x) {
  float a = __builtin_fabsf(x);
  float e = __expf(-2.0f * a);
  float r = __fdividef(1.0f - e, 1.0f + e);
  return __builtin_copysignf(r, x);
}
DEVI float sigmoidf_(float x) { return __fdividef(1.0f, 1.0f + __expf(-x)); }
DEVI float bflo(unsigned u) { return __uint_as_float(u << 16); }
DEVI float bfhi(unsigned u) { return __uint_as_float(u & 0xffff0000u); }
DEVI unsigned f2bf(float f) {
  unsigned u = __float_as_uint(f);
  return (u + 0x7fffu + ((u >> 16) & 1u)) >> 16;
}

DEVI float nc_ld_f1(const float* p) {
  float r;
  asm volatile("global_load_dword %0, %1, off sc0 sc1\n\ts_waitcnt vmcnt(0)"
               : "=&v"(r) : "v"(p) : "memory");
  return r;
}
DEVI f32x4 nc_ld4(const float* p) {
  f32x4 r;
  asm volatile("global_load_dwordx4 %0, %1, off sc0 sc1\n\ts_waitcnt vmcnt(0)"
               : "=&v"(r) : "v"(p) : "memory");
  return r;
}
DEVI void nc_ld4x2(const float* p0, const float* p1, f32x4& r0, f32x4& r1) {
  asm volatile(
      "global_load_dwordx4 %0, %2, off sc0 sc1\n\t"
      "global_load_dwordx4 %1, %3, off sc0 sc1\n\t"
      "s_waitcnt vmcnt(0)"
      : "=&v"(r0), "=&v"(r1) : "v"(p0), "v"(p1) : "memory");
}
DEVI void nc_st4(float* p, f32x4 v) {
  asm volatile("global_store_dwordx4 %0, %1, off sc0 sc1" :: "v"(p), "v"(v) : "memory");
}
DEVI void nc_st2u(ushort_t* p, u32x2 v) {
  asm volatile("global_store_dwordx2 %0, %1, off sc0 sc1" :: "v"(p), "v"(v) : "memory");
}
DEVI void nc_st_f1(float* p, float v_) {
  asm volatile("global_store_dword %0, %1, off sc0 sc1" :: "v"(p), "v"(v_) : "memory");
}

// 3-hop epoch-ring barrier: slot s = bk&3, use u = bk>>2, cumulative counters.
// grp[s][g] -> super[s] -> gen[s]; pollers poll gen[s] (ONE increment/use).
DEVI void bar_arrive(unsigned* bar, unsigned bk) {
  asm volatile("s_waitcnt vmcnt(0)" ::: "memory");
  __syncthreads();
  if (threadIdx.x == 0) {
    unsigned s = bk & 3u, u = bk >> 2;
    unsigned* grpc = bar + s * 512 + ((blockIdx.x >> 3) << 4);
    unsigned a = __hip_atomic_fetch_add(grpc, 1u, __ATOMIC_RELAXED, __HIP_MEMORY_SCOPE_AGENT);
    if (a == 8u * u + 7u) {
      unsigned t = __hip_atomic_fetch_add(bar + 2048 + s * 16, 1u, __ATOMIC_RELAXED, __HIP_MEMORY_SCOPE_AGENT);
      if (t == 32u * u + 31u)
        __hip_atomic_fetch_add(bar + 2112 + s * 16, 1u, __ATOMIC_RELAXED, __HIP_MEMORY_SCOPE_AGENT);
    }
  }
}
DEVI void bar_wait(unsigned* bar, unsigned bk) {
  if (threadIdx.x == 0) {
    unsigned s = bk & 3u, u = bk >> 2;
    while (__hip_atomic_load(bar + 2112 + s * 16, __ATOMIC_RELAXED, __HIP_MEMORY_SCOPE_AGENT) < u + 1u)
      __builtin_amdgcn_s_sleep(1);
  }
  __syncthreads();
}

// ---------- precompute Gh/Gw/Ge (f32) + gb ----------
__global__ __launch_bounds__(256) void kprepG(const float* __restrict__ attn_W,
                                              const float* __restrict__ fcW,
                                              const float* __restrict__ fcb,
                                              float* __restrict__ ws) {
  int bid = blockIdx.x, tid = threadIdx.x;
  if (bid < 288) {
    int rt = bid / 6, kt = bid % 6;
    int r0 = rt * 16;
    int kg = kt * 256 + tid;
    float acc[16];
#pragma unroll
    for (int q = 0; q < 16; ++q) acc[q] = 0.f;
    for (int o = 0; o < 384; ++o) {
      float f = fcW[o * 1536 + kg];
#pragma unroll
      for (int q = 0; q < 16; ++q)
        acc[q] = fmaf(attn_W[(r0 + q) * 1152 + 768 + o], f, acc[q]);
    }
#pragma unroll
    for (int q = 0; q < 16; ++q) {
      int r = r0 + q;
      if (kg < 768)       ws[OFF_GHM + r * 768 + kg] = acc[q];
      else if (kg < 1152) ws[OFF_GWM + r * 384 + (kg - 768)] = acc[q];
      else                ws[OFF_GEM + r * 384 + (kg - 1152)] = acc[q];
    }
  } else {
    for (int r = tid; r < 768; r += 256) {
      float a = 0.f;
      for (int o = 0; o < 384; ++o) a = fmaf(attn_W[r * 1152 + 768 + o], fcb[o], a);
      ws[OFF_GB + r] = a;
    }
  }
}

// ---------- prep: h transpose, zeros, M, barrier ----------
__global__ __launch_bounds__(256) void kprep0(const float* __restrict__ hidden,
                                              const float* __restrict__ vW,
                                              float* __restrict__ ws) {
  ushort_t* w16 = (ushort_t*)(ws + OFF_F32END);
  int bid = blockIdx.x, tid = threadIdx.x;
  int gtid = bid * 256 + tid;
  if (gtid < 24576) {
    int k = gtid >> 5, b = gtid & 31;
    ws[OFF_HALL + gtid] = hidden[b * 768 + k];
  } else if (gtid < 36864) {
    ((unsigned*)(w16 + O16_CALL))[gtid - 24576] = 0u;
  } else if (gtid < 43008) {
    ((unsigned*)(w16 + O16_HIST))[gtid - 36864] = 0u;
  }
  if (gtid < 2176) ((unsigned*)(ws + OFF_BAR))[gtid] = 0u;
  if (bid == 0) {
    __shared__ float vred[256];
    float a = 0.f;
    for (int k = tid; k < 768; k += 256) a += __builtin_fabsf(vW[k]);
    vred[tid] = a;
    __syncthreads();
    for (int s2 = 128; s2 > 0; s2 >>= 1) {
      if (tid < s2) vred[tid] += vred[tid + s2];
      __syncthreads();
    }
    if (tid == 0) ws[OFF_V1] = vred[0];
  }
}

// ---------- main persistent cooperative kernel ----------
__global__ void __launch_bounds__(1024)
kmain(const int* __restrict__ target, const float* __restrict__ emb,
      const float* __restrict__ attn_W, const float* __restrict__ attn_b,
      const float* __restrict__ vW,
      const float* __restrict__ Wih, const float* __restrict__ Whh,
      const float* __restrict__ bih, const float* __restrict__ bhh,
      const float* __restrict__ fcW, const float* __restrict__ fcb,
      float* __restrict__ outp, float* __restrict__ ws) {
  const int bid = blockIdx.x, tid = threadIdx.x;
  const int wv = tid >> 6, lane = tid & 63;
  const int b32 = lane & 31, kh = lane >> 5;
  const int vb = ((bid & 7) << 5) | (bid >> 3);  // XCD-major
  const int xcd = vb >> 5, slot = vb & 31;
  unsigned* bar = (unsigned*)(ws + OFF_BAR);
  ushort_t* w16 = (ushort_t*)(ws + OFF_F32END);

  // ---- LDS: persistent weights + phase-workspace union ----
  __shared__ __align__(16) float sW_A[8 * 768];    // 24.6 KB (phase A rows)
  __shared__ __align__(16) float sW_B[16 * 384];   // 24.6 KB (gie rows)
  __shared__ __align__(16) float sW_GH[12 * 768];  // 36.9 KB (Whh rows, B-right)
  __shared__ __align__(16) float sW_C[14 * 384];   // 21.5 KB
  __shared__ __align__(16) float sUn[13536];       // 54.1 KB

  // ---- row partitions ----
  const int gbA = (vb * 480) >> 8, geA = ((vb + 1) * 480) >> 8;
  const int rbA = gbA * 4;
  const int nswA = geA - gbA;            // 1 or 2
  const int nRA = nswA * 4;              // 4 or 8
  const int lb  = xcd * 28 + (slot - 4); // valid when slot>=4
  const int rbB = (slot >= 4) ? (lb * 3456) / 224 : 0;
  const int reB = (slot >= 4) ? ((lb + 1) * 3456) / 224 : 0;
  const int nB  = reB - rbB;
  const int gbG = (slot >= 4) ? (lb * 576) / 224 : 0;
  const int geG = (slot >= 4) ? ((lb + 1) * 576) / 224 : 0;
  const int nswG = geG - gbG;            // 2 or 3
  const int nRG = nswG * 4;              // 8 or 12
  const int rbC = xcd * 144 + ((slot * 144) >> 5);
  const int reC = xcd * 144 + (((slot + 1) * 144) >> 5);

  // ---- one-time LDS weight load ----
  for (int lr = 0; lr < nRA; ++lr) {
    int row = rbA + lr;
    const float* src;
    if (row < 768)       src = attn_W + row * 1152;
    else if (row < 1536) src = ws + OFF_GHM + (row - 768) * 768;
    else                 src = fcW + (row - 1536) * 1536;
    if (tid < 768) sW_A[lr * 768 + tid] = src[tid];
  }
  if (slot >= 4) {
    for (int lr = 0; lr < nB; ++lr) {
      int row = rbB + lr;
      const float* src;
      if (row < 2304)      src = Wih + row * 768;
      else if (row < 2688) src = fcW + (row - 2304) * 1536 + 1152;
      else                 src = ws + OFF_GEM + (row - 2688) * 384;
      if (tid < 384) sW_B[lr * 384 + tid] = src[tid];
    }
    for (int lr = 0; lr < nRG; ++lr) {
      int row = gbG * 4 + lr;
      if (tid < 768) sW_GH[lr * 768 + tid] = Whh[row * 768 + tid];
    }
  }
  for (int lr = 0; lr < 14; ++lr) {
    const float* src = nullptr;
    if (lr < 9) {
      int grow = vb * 3 + (lr / 3) + (lr % 3) * 768;  // lr = jl*3+gg
      src = Wih + grow * 768 + 384;
    } else {
      int r = rbC + (lr - 9);
      if (r < reC) src = (r < 384) ? fcW + r * 1536 + 768
                                   : ws + OFF_GWM + (r - 384) * 384;
    }
    if (src && tid < 384) sW_C[lr * 384 + tid] = src[tid];
  }
  __syncthreads();

  const float Mv = ws[OFF_V1];
  const int k0 = wv * 48 + kh * 24;
  unsigned bk = 0;

  for (int i = 0; i < 64; ++i) {
    // ======== Phase A (FUSED single pass): u, c_i, out_{i-1} ====
    {
      float* part_  = sUn;          // 4096 (16 waves x 8 rows x 32)
      float* stage  = sUn + 4096;   // 256
      float* stage2 = sUn + 4352;   // 256
      float xr[24];
      const float* hb = ws + OFF_HALL + i * 24576 + b32;  // (k,b) cached
#pragma unroll
      for (int q = 0; q < 24; ++q) xr[q] = hb[(k0 + q) * 32];

      float a[8];
#pragma unroll
      for (int r = 0; r < 8; ++r) a[r] = 0.f;
#pragma unroll
      for (int r = 0; r < 8; ++r) {
        if (r < nRA) {
          int row = rbA + r;
          if (!(i == 0 && row >= 768)) {
            const float* wp = &sW_A[r * 768 + k0];
            float acc = 0.f;
#pragma unroll
            for (int q = 0; q < 6; ++q) {
              f32x4 w = *(const f32x4*)(wp + q * 4);
              acc = fmaf(w[0], xr[q * 4 + 0], acc);
              acc = fmaf(w[1], xr[q * 4 + 1], acc);
              acc = fmaf(w[2], xr[q * 4 + 2], acc);
              acc = fmaf(w[3], xr[q * 4 + 3], acc);
            }
            a[r] = acc;
          }
        }
      }
#pragma unroll
      for (int r = 0; r < 8; ++r) a[r] += __shfl_xor(a[r], 32);
      if (kh == 0) {
#pragma unroll
        for (int r = 0; r < 8; ++r) part_[wv * 256 + r * 32 + b32] = a[r];
      }
      __syncthreads();
      if (tid < 256) {
        int rr = tid >> 5, bb = tid & 31;
        float sum = 0.f;
#pragma unroll
        for (int w2 = 0; w2 < 16; ++w2) sum += part_[w2 * 256 + tid];
        if (rr < nRA) {
          int row = rbA + rr;
          if (row < 768) sum += attn_b[row];
          stage[rr * 32 + bb] = sum;
        }
      } else if (tid < 320) {
        int t2 = tid - 256, rr = t2 >> 3, bq = t2 & 7;
        if (rr < nRA && i > 0) {
          int row = rbA + rr;
          if (row >= 768) {
            const float* src = row < 1536
                ? ws + OFF_CP + (row - 768) * 32 + bq * 4
                : ws + OFF_FP + (row - 1536) * 32 + bq * 4;
            *(f32x4*)&stage2[rr * 32 + bq * 4] = nc_ld4(src);
          }
        }
      }
      __syncthreads();
      if (tid < 64) {
        int gsel = tid >> 5, sub = tid & 31;
        if (gsel < nswA) {
          int row0 = rbA + gsel * 4;
          int e0 = gsel * 4;
          if (row0 < 768) {
            f32x4 v = {stage[e0 * 32 + sub], stage[(e0 + 1) * 32 + sub],
                       stage[(e0 + 2) * 32 + sub], stage[(e0 + 3) * 32 + sub]};
            nc_st4(ws + OFF_U + sub * 768 + row0, v);
          } else if (i > 0) {
            float v0 = stage[e0 * 32 + sub] + stage2[e0 * 32 + sub];
            float v1 = stage[(e0 + 1) * 32 + sub] + stage2[(e0 + 1) * 32 + sub];
            float v2 = stage[(e0 + 2) * 32 + sub] + stage2[(e0 + 2) * 32 + sub];
            float v3 = stage[(e0 + 3) * 32 + sub] + stage2[(e0 + 3) * 32 + sub];
            u32x2 pk;
            pk[0] = f2bf(v0) | (f2bf(v1) << 16);
            pk[1] = f2bf(v2) | (f2bf(v3) << 16);
            if (row0 < 1536) {
              nc_st2u(w16 + O16_CALL + i * 24576 + sub * 768 + (row0 - 768), pk);
            } else {
              nc_st2u(w16 + O16_HIST + i * 12288 + sub * 384 + (row0 - 1536), pk);
              f32x4 vf = {v0, v1, v2, v3};
              nc_st4(ws + OFF_HISTF + i * 12288 + sub * 384 + (row0 - 1536), vf);
            }
          }
        }
      }
    }
    bar_arrive(bar, bk);  // split barrier 1: gie+gh blocks do NOT wait

    // ======== Phase B: attention (32 blocks, waits) | gie + gh (224, no wait) ====
    if (slot < 4) {
      bar_wait(bar, bk);
      const int bb = xcd * 4 + (vb & 3);
      float* u_s   = sUn;           // 768
      float* p_l   = sUn + 768;     // 64
      float* d_l   = sUn + 832;     // 16 (pad)
      float* wred2 = sUn + 848;     // 1536 (4 t-parities x 384)
      if (tid < 192) *(f32x4*)&u_s[tid * 4] = nc_ld4(ws + OFF_U + bb * 768 + tid * 4);
      if (tid < 64) p_l[tid] = 0.f;
      __syncthreads();
      const int tl = tid >> 5, kc = tid & 31;
      float u_r[24], v_r[24];
#pragma unroll
      for (int q = 0; q < 24; ++q) {
        u_r[q] = u_s[kc * 24 + q];
        v_r[q] = vW[kc * 24 + q];
      }
#pragma unroll
      for (int rr2 = 0; rr2 < 2; ++rr2) {
        int t = rr2 * 32 + tl;
        float s = 0.f;
        if (t <= i) {
          const ushort_t* cb = w16 + O16_CALL + t * 24576 + bb * 768 + kc * 24;  // cached
          u32x4 c0 = ((const u32x4*)cb)[0];
          u32x4 c1 = ((const u32x4*)cb)[1];
          u32x4 c2 = ((const u32x4*)cb)[2];
#pragma unroll
          for (int j = 0; j < 4; ++j) {
            s = fmaf(fast_tanh(u_r[2 * j] + bflo(c0[j])), v_r[2 * j], s);
            s = fmaf(fast_tanh(u_r[2 * j + 1] + bfhi(c0[j])), v_r[2 * j + 1], s);
            s = fmaf(fast_tanh(u_r[8 + 2 * j] + bflo(c1[j])), v_r[8 + 2 * j], s);
            s = fmaf(fast_tanh(u_r[8 + 2 * j + 1] + bfhi(c1[j])), v_r[8 + 2 * j + 1], s);
            s = fmaf(fast_tanh(u_r[16 + 2 * j] + bflo(c2[j])), v_r[16 + 2 * j], s);
            s = fmaf(fast_tanh(u_r[16 + 2 * j + 1] + bfhi(c2[j])), v_r[16 + 2 * j + 1], s);
          }
        }
#pragma unroll
        for (int d2 = 16; d2 >= 1; d2 >>= 1) s += __shfl_xor(s, d2);
        if (kc == 0 && t <= i) p_l[t] = __expf(s - Mv);
      }
      __syncthreads();
      if (tid < 64) {
        float pv = p_l[tid];
#pragma unroll
        for (int d = 1; d < 64; d <<= 1) pv += __shfl_xor(pv, d);
        if (tid == 0) d_l[0] = __fdividef(1.0f, pv);
      }
      __syncthreads();
      float dinv = d_l[0];
      if (tid >= 768 && tid < 832) {
        int t = tid - 768;
        if (t <= i)
          outp[ATTN_OFF + bb * 2080 + (i * (i + 1)) / 2 + t] = p_l[t] * dinv;
      }
      if (tid < 768) {
        int opair = tid % 192, tpar = tid / 192;  // tpar 0..3
        int o0 = opair * 2;
        const ushort_t* hbase = w16 + O16_HIST + bb * 384 + o0;
        float a0 = 0.f, a1 = 0.f;
        int t = tpar;
        for (; t + 4 <= i; t += 8) {
          unsigned hv0 = *(const unsigned*)(hbase + t * 12288);
          unsigned hv1 = *(const unsigned*)(hbase + (t + 4) * 12288);
          float p0 = p_l[t], p1 = p_l[t + 4];
          a0 = fmaf(p0, bflo(hv0), a0);
          a1 = fmaf(p0, bfhi(hv0), a1);
          a0 = fmaf(p1, bflo(hv1), a0);
          a1 = fmaf(p1, bfhi(hv1), a1);
        }
        if (t <= i) {
          unsigned hv = *(const unsigned*)(hbase + t * 12288);
          float p = p_l[t];
          a0 = fmaf(p, bflo(hv), a0);
          a1 = fmaf(p, bfhi(hv), a1);
        }
        wred2[tpar * 384 + o0]     = a0;
        wred2[tpar * 384 + o0 + 1] = a1;
      }
      __syncthreads();
      if (tid < 96) {
        f32x4 v;
#pragma unroll
        for (int e = 0; e < 4; ++e) {
          int o = tid * 4 + e;
          v[e] = (wred2[o] + wred2[384 + o] + wred2[768 + o] + wred2[1152 + o]) * dinv;
        }
        nc_st4(ws + OFF_WALL + i * 12288 + bb * 384 + tid * 4, v);
      }
    } else {
      // gie+gh proceed immediately (inputs: token emb + h_i, both ready)
      float* part_  = sUn;          // gie: 2048 / gh: 6144
      float* stageB = sUn + 2048;   // 512
      float* ghst   = sUn + 8192;   // 384
      const int gl = wv >> 2, kq = wv & 3;
      const int tok = target[b32 * 65 + i];
      const int koff = kq * 96 + kh * 48;
      const float* xe = emb + tok * 384 + koff;
      f32x4 x_[12];
#pragma unroll
      for (int q = 0; q < 12; ++q) x_[q] = *(const f32x4*)(xe + q * 4);
      float a[4];
#pragma unroll
      for (int r = 0; r < 4; ++r) {
        int lr = gl * 4 + r;
        float acc = 0.f;
        if (lr < nB) {
          const float* wp = &sW_B[lr * 384 + koff];
#pragma unroll
          for (int q = 0; q < 12; ++q) {
            f32x4 w = *(const f32x4*)(wp + q * 4);
            acc = fmaf(w[0], x_[q][0], acc);
            acc = fmaf(w[1], x_[q][1], acc);
            acc = fmaf(w[2], x_[q][2], acc);
            acc = fmaf(w[3], x_[q][3], acc);
          }
        }
        a[r] = acc;
      }
#pragma unroll
      for (int r = 0; r < 4; ++r) a[r] += __shfl_xor(a[r], 32);
      if (kh == 0) {
#pragma unroll
        for (int r = 0; r < 4; ++r)
          part_[((gl * 4 + r) * 4 + kq) * 32 + b32] = a[r];
      }
      __syncthreads();
      if (tid < 512) {
        int glr = tid >> 5, bb = tid & 31;
        if (glr < nB) {
          float sum = part_[(glr * 4 + 0) * 32 + bb] + part_[(glr * 4 + 1) * 32 + bb]
                    + part_[(glr * 4 + 2) * 32 + bb] + part_[(glr * 4 + 3) * 32 + bb];
          int row = rbB + glr;
          if (row < 2304) sum += bih[row];
          else if (row < 2688) sum += fcb[row - 2304];
          else sum += ws[OFF_GB + (row - 2688)];
          stageB[glr * 32 + bb] = sum;
        }
      }
      __syncthreads();
      if (tid < 128) {
        int r16 = tid >> 3, bq = tid & 7;
        if (r16 < nB) {
          int row = rbB + r16;
          f32x4 v = *(f32x4*)&stageB[r16 * 32 + bq * 4];
          float* dst;
          if (row < 2304) dst = ws + OFF_GIE + row * 32 + bq * 4;
          else if (row < 2688) dst = ws + OFF_FE + (row - 2304) * 32 + bq * 4;
          else dst = ws + OFF_GE + (row - 2688) * 32 + bq * 4;
          nc_st4(dst, v);
        }
      }
      __syncthreads();
      // ---- gh pass (FUSED): Whh·h_i + bhh, up to 12 rows in one pass ----
      {
        float xr2[24];
        const float* hb2 = ws + OFF_HALL + i * 24576 + b32;  // cached
#pragma unroll
        for (int q = 0; q < 24; ++q) xr2[q] = hb2[(k0 + q) * 32];
        float a2[12];
#pragma unroll
        for (int r = 0; r < 12; ++r) a2[r] = 0.f;
#pragma unroll
        for (int r = 0; r < 12; ++r) {
          if (r < nRG) {
            const float* wp = &sW_GH[r * 768 + k0];
            float acc = 0.f;
#pragma unroll
            for (int q = 0; q < 6; ++q) {
              f32x4 w = *(const f32x4*)(wp + q * 4);
              acc = fmaf(w[0], xr2[q * 4 + 0], acc);
              acc = fmaf(w[1], xr2[q * 4 + 1], acc);
              acc = fmaf(w[2], xr2[q * 4 + 2], acc);
              acc = fmaf(w[3], xr2[q * 4 + 3], acc);
            }
            a2[r] = acc;
          }
        }
#pragma unroll
        for (int r = 0; r < 12; ++r) a2[r] += __shfl_xor(a2[r], 32);
        if (kh == 0) {
#pragma unroll
          for (int r = 0; r < 12; ++r) part_[wv * 384 + r * 32 + b32] = a2[r];
        }
        __syncthreads();
        if (tid < 384) {
          int rr = tid >> 5, bb = tid & 31;
          if (rr < nRG) {
            float sum = 0.f;
#pragma unroll
            for (int w2 = 0; w2 < 16; ++w2) sum += part_[w2 * 384 + tid];
            ghst[rr * 32 + bb] = sum + bhh[gbG * 4 + rr];
          }
        }
        __syncthreads();
        if (tid < 96) {
          int rr = tid >> 3, bq = tid & 7;
          if (rr < nRG)
            nc_st4(ws + OFF_GH + (gbG * 4 + rr) * 32 + bq * 4,
                   *(f32x4*)&ghst[rr * 32 + bq * 4]);
        }
      }
    }
    ++bk;
    bar_arrive(bar, bk);
    bar_wait(bar, bk);
    ++bk;

    // ======== Phase C: w staging, giw, fpart/cpart, gates ====
    {
      float* w_lds   = sUn;           // 12416 (stride 388)
      float* g_lds   = sUn + 12416;   // 576
      float* giw_lds = sUn + 12992;   // 288
      float* fpst    = sUn + 13280;   // 160
      float* gat     = sUn + 13440;   // 96
      {
        int b = tid >> 5, c = tid & 31;
        const float* src = ws + OFF_WALL + i * 12288 + tid * 12;  // cached coalesced
        float* dst = w_lds + b * 388 + c * 12;
        *(f32x4*)&dst[0] = *(const f32x4*)(src);
        *(f32x4*)&dst[4] = *(const f32x4*)(src + 4);
        *(f32x4*)&dst[8] = *(const f32x4*)(src + 8);
      }
      __syncthreads();
      if (wv < 9) {
        int jl = wv / 3, gg = wv % 3;
        const float* wp = &sW_C[(jl * 3 + gg) * 384 + kh * 192];
        const float* xp = w_lds + b32 * 388 + kh * 192;
        float acc = 0.f;
#pragma unroll 8
        for (int q = 0; q < 48; ++q) {
          f32x4 wq4 = *(const f32x4*)(wp + q * 4);
          f32x4 xq4 = *(const f32x4*)(xp + q * 4);
          acc = fmaf(wq4[0], xq4[0], acc); acc = fmaf(wq4[1], xq4[1], acc);
          acc = fmaf(wq4[2], xq4[2], acc); acc = fmaf(wq4[3], xq4[3], acc);
        }
        acc += __shfl_xor(acc, 32);
        if (kh == 0) giw_lds[(jl * 3 + gg) * 32 + b32] = acc;
      } else if (wv < 14) {
        int r = rbC + (wv - 9);
        if (r < reC) {
          const float* wp = &sW_C[(9 + (wv - 9)) * 384 + kh * 192];
          const float* xp = w_lds + b32 * 388 + kh * 192;
          float acc = 0.f;
#pragma unroll 8
          for (int q = 0; q < 48; ++q) {
            f32x4 wq4 = *(const f32x4*)(wp + q * 4);
            f32x4 xq4 = *(const f32x4*)(xp + q * 4);
            acc = fmaf(wq4[0], xq4[0], acc); acc = fmaf(wq4[1], xq4[1], acc);
            acc = fmaf(wq4[2], xq4[2], acc); acc = fmaf(wq4[3], xq4[3], acc);
          }
          acc += __shfl_xor(acc, 32);
          if (kh == 0) fpst[(wv - 9) * 32 + b32] = acc;
        }
      } else {
        int t2 = tid - 896;
        if (t2 < 72) {
          int q0 = 2 * t2, q1 = 2 * t2 + 1;
          const float* pa;
          const float* pb;
          {
            int row = q0 >> 3, bq = q0 & 7;
            int rr2 = row < 9 ? row : row - 9;
            int r = vb * 3 + (rr2 % 3) + (rr2 / 3) * 768;
            pa = ws + (row < 9 ? OFF_GIE : OFF_GH) + r * 32 + bq * 4;
          }
          {
            int row = q1 >> 3, bq = q1 & 7;
            int rr2 = row < 9 ? row : row - 9;
            int r = vb * 3 + (rr2 % 3) + (rr2 / 3) * 768;
            pb = ws + (row < 9 ? OFF_GIE : OFF_GH) + r * 32 + bq * 4;
          }
          f32x4 v0, v1;
          nc_ld4x2(pa, pb, v0, v1);
          *(f32x4*)&g_lds[q0 * 4] = v0;
          *(f32x4*)&g_lds[q1 * 4] = v1;
        }
      }
      __syncthreads();
      if (tid < 96) {
        int jl = tid >> 5, bb = tid & 31;
        int j = vb * 3 + jl;
        float gi_r = g_lds[jl * 32 + bb];
        float gi_z = g_lds[(3 + jl) * 32 + bb];
        float gi_n = g_lds[(6 + jl) * 32 + bb];
        float gh_r = g_lds[(9 + jl) * 32 + bb];
        float gh_z = g_lds[(12 + jl) * 32 + bb];
        float gh_n = g_lds[(15 + jl) * 32 + bb];
        float giw_r = giw_lds[(jl * 3 + 0) * 32 + bb];
        float giw_z = giw_lds[(jl * 3 + 1) * 32 + bb];
        float giw_n = giw_lds[(jl * 3 + 2) * 32 + bb];
        float hold = ws[OFF_HALL + i * 24576 + j * 32 + bb];
        float r_ = sigmoidf_(gi_r + giw_r + gh_r);
        float z_ = sigmoidf_(gi_z + giw_z + gh_z);
        float n_ = fast_tanh(fmaf(r_, gh_n, gi_n + giw_n));
        gat[jl * 32 + bb] = (1.0f - z_) * n_ + z_ * hold;
      } else if (tid >= 96 && tid < 136) {
        int t2 = tid - 96, rl = t2 >> 3, bq = t2 & 7;
        int r = rbC + rl;
        if (r < reC) {
          const float* addp = r < 384 ? ws + OFF_FE + r * 32 + bq * 4
                                      : ws + OFF_GE + (r - 384) * 32 + bq * 4;
          f32x4 ad = nc_ld4(addp);
          f32x4 v;
#pragma unroll
          for (int e = 0; e < 4; ++e) v[e] = fpst[rl * 32 + bq * 4 + e] + ad[e];
          float* dst = r < 384 ? ws + OFF_FP + r * 32 + bq * 4
                               : ws + OFF_CP + (r - 384) * 32 + bq * 4;
          nc_st4(dst, v);
        }
      }
      __syncthreads();
      if (tid < 24) {
        int jl3 = tid >> 3, bq = tid & 7;
        f32x4 v = *(f32x4*)&gat[jl3 * 32 + bq * 4];
        nc_st4(ws + OFF_HALL + (i + 1) * 24576 + (vb * 3 + jl3) * 32 + bq * 4, v);
      }
    }
    bar_arrive(bar, bk);
    bar_wait(bar, bk);
    ++bk;
  }

  // ======== epilogue: out_63 = F_h h_64 + fp_63 ====
  if (slot < 3) {
    int o = xcd * 48 + slot * 16 + wv;
    const float* hcol = ws + OFF_HALL + 64 * 24576 + b32;
    const float* wrow = fcW + o * 1536 + kh * 384;
    float acc = 0.f;
#pragma unroll 4
    for (int q = 0; q < 96; ++q) {
      f32x4 wq = *(const f32x4*)(wrow + q * 4);
      int k = kh * 384 + q * 4;
      acc = fmaf(wq[0], hcol[k * 32], acc);
      acc = fmaf(wq[1], hcol[(k + 1) * 32], acc);
      acc = fmaf(wq[2], hcol[(k + 2) * 32], acc);
      acc = fmaf(wq[3], hcol[(k + 3) * 32], acc);
    }
    acc += __shfl_xor(acc, 32);
    if (kh == 0) {
      float fp = nc_ld_f1(ws + OFF_FP + o * 32 + b32);
      outp[b32 * 24576 + o * 64 + 63] = acc + fp;
    }
  }
  // ======== final transpose: outputs[b][o][t], t=0..62 from HISTF ====
  if (tid < 48) {
    int pair = vb * 48 + tid;
    int b = pair / 384, o = pair - b * 384;
    const float* src = ws + OFF_HISTF + b * 384 + o;
    float* dst = outp + b * 24576 + o * 64;
#pragma unroll 7
    for (int t = 0; t < 63; ++t) dst[t] = src[(t + 1) * 12288];
  }
}

extern "C" void kernel_launch(void* const* d_in, const int* in_sizes, int n_in,
                              void* d_out, int out_size, void* d_ws, size_t ws_size,
                              hipStream_t stream) {
  const int*   target = (const int*)d_in[0];
  const float* hidden = (const float*)d_in[1];
  // d_in[2] = teacher_forcing_ratio (== 1, deterministic path)
  const float* emb    = (const float*)d_in[3];
  const float* attn_W = (const float*)d_in[4];
  const float* attn_b = (const float*)d_in[5];
  const float* vW     = (const float*)d_in[6];
  const float* Wih    = (const float*)d_in[7];
  const float* Whh    = (const float*)d_in[8];
  const float* bih    = (const float*)d_in[9];
  const float* bhh    = (const float*)d_in[10];
  const float* fcW    = (const float*)d_in[11];
  const float* fcb    = (const float*)d_in[12];
  float* outp = (float*)d_out;
  float* ws   = (float*)d_ws;

  kprepG<<<289, 256, 0, stream>>>(attn_W, fcW, fcb, ws);
  kprep0<<<256, 256, 0, stream>>>(hidden, vW, ws);

  void* args[] = {(void*)&target, (void*)&emb, (void*)&attn_W, (void*)&attn_b,
                  (void*)&vW, (void*)&Wih, (void*)&Whh, (void*)&bih, (void*)&bhh,
                  (void*)&fcW, (void*)&fcb, (void*)&outp, (void*)&ws};
  hipLaunchCooperativeKernel((const void*)kmain, dim3(256), dim3(1024), args, 0, stream);
}